// Round 10
// baseline (197.787 us; speedup 1.0000x reference)
//
#include <hip/hip_runtime.h>
#include <hip/hip_bf16.h>
#include <math.h>

#define T_ 4
#define B_ 8
#define C_ 256
#define HID_ 1024
#define E_ 8
#define HW_ 196
#define M_ 784            // T*HW rows per (b,expert) pair, r = hw*4 + t
#define NPAIR_ 16
#define EPS_ 1e-5f
#define NOUT_ (T_*B_*C_*HW_)   // 1,605,632 floats

typedef __attribute__((ext_vector_type(8))) short bf16x8;
typedef __attribute__((ext_vector_type(4))) unsigned short u16x4;
typedef __attribute__((ext_vector_type(4))) float f32x4;

__device__ inline unsigned short f2bf(float f){
  union { float f; unsigned u; } v; v.f = f;
  unsigned u = v.u;
  unsigned r = u + 0x7FFFu + ((u >> 16) & 1u);   // RNE
  return (unsigned short)(r >> 16);
}
__device__ inline float bf2f(unsigned short h){
  union { unsigned u; float f; } v; v.u = ((unsigned)h) << 16;
  return v.f;
}

// direct global->LDS, 16B/lane; LDS dest = wave-uniform base + lane*16
__device__ inline void gl16(const void* g, void* l){
  auto gp = reinterpret_cast<const unsigned int __attribute__((address_space(1)))*>(
      reinterpret_cast<uintptr_t>(g));
  auto lp = reinterpret_cast<unsigned int __attribute__((address_space(3)))*>(
      reinterpret_cast<uintptr_t>(l));
  __builtin_amdgcn_global_load_lds(gp, lp, 16, 0, 0);
}

// ---- both weight conversions in one pass ----
__global__ __launch_bounds__(256) void wconv_kernel(
    const float* __restrict__ w1, const float* __restrict__ w2,
    unsigned short* __restrict__ w1h, unsigned short* __restrict__ w1l,
    unsigned short* __restrict__ w2h){
  int i = blockIdx.x * 256 + threadIdx.x;      // over NW/4
  float4 v = ((const float4*)w1)[i];
  u16x4 h, l;
  h[0]=f2bf(v.x); l[0]=f2bf(v.x - bf2f(h[0]));
  h[1]=f2bf(v.y); l[1]=f2bf(v.y - bf2f(h[1]));
  h[2]=f2bf(v.z); l[2]=f2bf(v.z - bf2f(h[2]));
  h[3]=f2bf(v.w); l[3]=f2bf(v.w - bf2f(h[3]));
  ((u16x4*)w1h)[i] = h; ((u16x4*)w1l)[i] = l;
  float4 u = ((const float4*)w2)[i];
  u16x4 h2;
  h2[0]=f2bf(u.x); h2[1]=f2bf(u.y); h2[2]=f2bf(u.z); h2[3]=f2bf(u.w);
  ((u16x4*)w2h)[i] = h2;
}

// ---- xbar[b,c] = mean over (t,hw) of x ----
__global__ __launch_bounds__(64) void xbar_kernel(const float* __restrict__ x,
                                                  float* __restrict__ xbar){
  int bc = blockIdx.x;
  int l = threadIdx.x;
  float s = 0.f;
  for (int t = 0; t < T_; t++){
    const float* p = x + ((size_t)(t * B_ * C_) + bc) * HW_;
    for (int i = l; i < HW_; i += 64) s += p[i];
  }
  for (int off = 32; off > 0; off >>= 1) s += __shfl_down(s, off, 64);
  if (l == 0) xbar[bc] = s * (1.0f / (T_ * HW_));
}

// ---- router: logits -> softmax -> top2 ----
__global__ __launch_bounds__(64) void router_kernel(const float* __restrict__ xbar,
    const float* __restrict__ rw, const float* __restrict__ rb,
    const float* __restrict__ rg, const float* __restrict__ rbb,
    const float* __restrict__ rm, const float* __restrict__ rv,
    int* __restrict__ sel_e, float* __restrict__ sel_w){
  __shared__ float lg[64];
  const int tid = threadIdx.x;
  const int b = tid >> 3, e = tid & 7;
  float dot = 0.f;
  for (int c = 0; c < C_; c++) dot += xbar[b * C_ + c] * rw[e * C_ + c];
  dot += rb[e];
  float sc = rg[e] / sqrtf(rv[e] + EPS_);
  lg[tid] = (dot - rm[e]) * sc + rbb[e];
  __syncthreads();
  if (e == 0){
    float l[E_], mx = -1e30f;
    for (int i = 0; i < E_; i++){ l[i] = lg[b * 8 + i]; mx = fmaxf(mx, l[i]); }
    float p[E_];
    for (int i = 0; i < E_; i++) p[i] = expf(l[i] - mx);
    int i1 = 0;
    for (int i = 1; i < E_; i++) if (p[i] > p[i1]) i1 = i;
    int i2 = (i1 == 0) ? 1 : 0;
    for (int i = 0; i < E_; i++) if (i != i1 && p[i] > p[i2]) i2 = i;
    float denom = p[i1] + p[i2];
    sel_e[b * 2]     = i1; sel_w[b * 2]     = p[i1] / denom;
    sel_e[b * 2 + 1] = i2; sel_w[b * 2 + 1] = p[i2] / denom;
  }
}

// ---- LIF1: x -> s1 spikes, layout s1[pair][hw*4+t][c] ----
__global__ __launch_bounds__(256) void lif1_kernel(const float* __restrict__ x,
    const int* __restrict__ sel_e, const float* __restrict__ taus,
    unsigned short* __restrict__ s1){
  const int hw = blockIdx.x;
  const int pair = blockIdx.y;
  const int c = threadIdx.x;
  const int b = pair >> 1;
  const float tau = taus[sel_e[pair]];
  float v = 0.f;
  #pragma unroll
  for (int t = 0; t < T_; t++){
    float xv = x[((size_t)(t * B_ + b) * C_ + c) * HW_ + hw];
    float h = v + (xv - v) / tau;
    float s = (h >= 1.0f) ? 1.0f : 0.0f;
    v = h * (1.0f - s);
    s1[((size_t)pair * M_ + hw * 4 + t) * C_ + c] =
        (s > 0.5f) ? (unsigned short)0x3F80 : (unsigned short)0;
  }
}

// Bank swizzle: LDS tile [64 rows][32 u16], 16B slot s of row r stored at
// phys slot s ^ (r&3) ^ ((r>>2)&1). Staging pre-swizzles the GLOBAL source
// column (rule: inverse-swz source + swz read, LDS dest stays linear).
// Verified: read pattern lands 64 lanes on 32 banks at 2/bank (free).

// ---- GEMM1: grid (nt16, mt13, pair16); 48KB LDS 4-buf ring; counted vmcnt;
// hi/lo MFMA; BN1+LIF2 in-register epilogue -> s2 ----
__global__ __launch_bounds__(256) void g1_kernel(
    const unsigned short* __restrict__ s1,
    const unsigned short* __restrict__ w1h, const unsigned short* __restrict__ w1l,
    const float* __restrict__ fc1_b,
    const float* __restrict__ bn1_g, const float* __restrict__ bn1_b,
    const float* __restrict__ bn1_m, const float* __restrict__ bn1_v,
    const int* __restrict__ sel_e, const float* __restrict__ taus,
    unsigned short* __restrict__ s2)
{
  __shared__ __align__(16) unsigned short lA[4][2048];
  __shared__ __align__(16) unsigned short lBh[4][2048];
  __shared__ __align__(16) unsigned short lBl[4][2048];
  const int nt = blockIdx.x, mt = blockIdx.y, pair = blockIdx.z;
  const int e = sel_e[pair];
  const int m0 = mt * 64, n0 = nt * 64;
  const int tid = threadIdx.x, lane = tid & 63, wv = tid >> 6;
  const int l15 = lane & 15;
  // swizzled read offset: same XOR for A and B reads (row bits 0..3 only)
  const int koffs = ((((lane >> 4) ^ (l15 & 3) ^ ((l15 >> 2) & 1)) & 3) << 3);
  // staging: lane i -> row wv*16+(i>>2); source col-slot pre-swizzled
  const int srow = wv * 16 + (lane >> 2);
  const int scol = ((((lane & 3) ^ ((lane >> 2) & 3) ^ ((lane >> 4) & 1)) & 3) << 3);
  int arow = m0 + srow; if (arow > M_ - 1) arow = M_ - 1;   // clamp; dup discarded
  const unsigned short* aG  = s1  + ((size_t)pair * M_ + arow) * C_ + scol;
  const unsigned short* bhG = w1h + ((size_t)e * HID_ + n0 + srow) * C_ + scol;
  const unsigned short* blG = w1l + ((size_t)e * HID_ + n0 + srow) * C_ + scol;
  const int lb = wv * 512;                                  // u16 units
  #pragma unroll
  for (int p = 0; p < 3; p++){                              // prologue L(0..2)
    gl16(aG  + p * 32, &lA[p][lb]);
    gl16(bhG + p * 32, &lBh[p][lb]);
    gl16(blG + p * 32, &lBl[p][lb]);
  }
  f32x4 acc[4] = {};
  #pragma unroll
  for (int kk = 0; kk < 8; kk++){
    if (kk < 6)       asm volatile("s_waitcnt vmcnt(6)" ::: "memory");
    else if (kk == 6) asm volatile("s_waitcnt vmcnt(3)" ::: "memory");
    else              asm volatile("s_waitcnt vmcnt(0)" ::: "memory");
    __builtin_amdgcn_s_barrier();
    __builtin_amdgcn_sched_barrier(0);    // fence: no prefetch hoists above barrier
    const int cur = kk & 3;
    bf16x8 a = *(const bf16x8*)(&lA[cur][(wv * 16 + l15) * 32 + koffs]);
    #pragma unroll
    for (int cb = 0; cb < 4; cb++){
      bf16x8 bh = *(const bf16x8*)(&lBh[cur][(cb * 16 + l15) * 32 + koffs]);
      bf16x8 bl = *(const bf16x8*)(&lBl[cur][(cb * 16 + l15) * 32 + koffs]);
      acc[cb] = __builtin_amdgcn_mfma_f32_16x16x32_bf16(a, bh, acc[cb], 0, 0, 0);
      acc[cb] = __builtin_amdgcn_mfma_f32_16x16x32_bf16(a, bl, acc[cb], 0, 0, 0);
    }
    if (kk < 5){
      const int nb = (kk + 3) & 3;
      gl16(aG  + (kk + 3) * 32, &lA[nb][lb]);
      gl16(bhG + (kk + 3) * 32, &lBh[nb][lb]);
      gl16(blG + (kk + 3) * 32, &lBl[nb][lb]);
    }
  }
  const float tau = taus[e];
  const int rbase = m0 + wv * 16 + ((lane >> 4) << 2);
  if (rbase < M_){
    #pragma unroll
    for (int cb = 0; cb < 4; cb++){
      int col = n0 + cb * 16 + l15;
      int pi = e * HID_ + col;
      float sc = bn1_g[pi] / sqrtf(bn1_v[pi] + EPS_);
      float mm = bn1_m[pi], bb = bn1_b[pi], cbias = fc1_b[pi];
      float v = 0.f;
      #pragma unroll
      for (int t = 0; t < 4; t++){
        float z = acc[cb][t] + cbias;
        float hin = (z - mm) * sc + bb;
        float h = v + (hin - v) / tau;
        float s = (h >= 1.0f) ? 1.0f : 0.0f;
        v = h * (1.0f - s);
        s2[((size_t)pair * M_ + rbase + t) * HID_ + col] =
            (s > 0.5f) ? (unsigned short)0x3F80 : (unsigned short)0;
      }
    }
  }
}

// ---- GEMM2: grid (nt4, mt13, pair16); 32KB LDS 4-buf ring; counted vmcnt;
// hi-only; weighted BN2 output -> y[slot] in out-layout ----
__global__ __launch_bounds__(256) void g2_kernel(
    const unsigned short* __restrict__ s2,
    const unsigned short* __restrict__ w2h,
    const float* __restrict__ fc2_b,
    const float* __restrict__ bn2_g, const float* __restrict__ bn2_b,
    const float* __restrict__ bn2_m, const float* __restrict__ bn2_v,
    const int* __restrict__ sel_e, const float* __restrict__ sel_w,
    float* __restrict__ y)
{
  __shared__ __align__(16) unsigned short lA[4][2048];
  __shared__ __align__(16) unsigned short lBh[4][2048];
  const int nt = blockIdx.x, mt = blockIdx.y, pair = blockIdx.z;
  const int e = sel_e[pair];
  const float wgt = sel_w[pair];
  const int b = pair >> 1, slot = pair & 1;
  const int m0 = mt * 64, n0 = nt * 64;
  const int tid = threadIdx.x, lane = tid & 63, wv = tid >> 6;
  const int l15 = lane & 15;
  const int koffs = ((((lane >> 4) ^ (l15 & 3) ^ ((l15 >> 2) & 1)) & 3) << 3);
  const int srow = wv * 16 + (lane >> 2);
  const int scol = ((((lane & 3) ^ ((lane >> 2) & 3) ^ ((lane >> 4) & 1)) & 3) << 3);
  int arow = m0 + srow; if (arow > M_ - 1) arow = M_ - 1;
  const unsigned short* aG  = s2  + ((size_t)pair * M_ + arow) * HID_ + scol;
  const unsigned short* bhG = w2h + ((size_t)e * C_ + n0 + srow) * HID_ + scol;
  const int lb = wv * 512;
  #pragma unroll
  for (int p = 0; p < 3; p++){
    gl16(aG  + p * 32, &lA[p][lb]);
    gl16(bhG + p * 32, &lBh[p][lb]);
  }
  f32x4 acc[4] = {};
  #pragma unroll
  for (int kk = 0; kk < 32; kk++){
    if (kk < 30)       asm volatile("s_waitcnt vmcnt(4)" ::: "memory");
    else if (kk == 30) asm volatile("s_waitcnt vmcnt(2)" ::: "memory");
    else               asm volatile("s_waitcnt vmcnt(0)" ::: "memory");
    __builtin_amdgcn_s_barrier();
    __builtin_amdgcn_sched_barrier(0);
    const int cur = kk & 3;
    bf16x8 a = *(const bf16x8*)(&lA[cur][(wv * 16 + l15) * 32 + koffs]);
    #pragma unroll
    for (int cb = 0; cb < 4; cb++){
      bf16x8 bh = *(const bf16x8*)(&lBh[cur][(cb * 16 + l15) * 32 + koffs]);
      acc[cb] = __builtin_amdgcn_mfma_f32_16x16x32_bf16(a, bh, acc[cb], 0, 0, 0);
    }
    if (kk < 29){
      const int nb = (kk + 3) & 3;
      gl16(aG  + (kk + 3) * 32, &lA[nb][lb]);
      gl16(bhG + (kk + 3) * 32, &lBh[nb][lb]);
    }
  }
  const int rbase = m0 + wv * 16 + ((lane >> 4) << 2);
  if (rbase < M_){
    const int hw = rbase >> 2;
    #pragma unroll
    for (int cb = 0; cb < 4; cb++){
      int col = n0 + cb * 16 + l15;
      int pi = e * C_ + col;
      float sc = bn2_g[pi] / sqrtf(bn2_v[pi] + EPS_);
      float mm = bn2_m[pi], bb = bn2_b[pi], cbias = fc2_b[pi];
      #pragma unroll
      for (int t = 0; t < 4; t++){
        float z = acc[cb][t] + cbias;
        float yv = (z - mm) * sc + bb;
        y[(((size_t)slot * T_ + t) * B_ + b) * (C_ * HW_) + (size_t)col * HW_ + hw] =
            wgt * yv;
      }
    }
  }
}

// ---- out = x + y0 + y1 ----
__global__ __launch_bounds__(256) void combine_kernel(const float* __restrict__ x,
    const float* __restrict__ y, float* __restrict__ out){
  int i = blockIdx.x * 256 + threadIdx.x;
  float4 a  = ((const float4*)x)[i];
  float4 b0 = ((const float4*)y)[i];
  float4 b1 = ((const float4*)y)[i + NOUT_ / 4];
  float4 r;
  r.x = a.x + b0.x + b1.x;
  r.y = a.y + b0.y + b1.y;
  r.z = a.z + b0.z + b1.z;
  r.w = a.w + b0.w + b1.w;
  ((float4*)out)[i] = r;
}

extern "C" void kernel_launch(void* const* d_in, const int* in_sizes, int n_in,
                              void* d_out, int out_size, void* d_ws, size_t ws_size,
                              hipStream_t stream){
  const float* x     = (const float*)d_in[0];
  const float* rw    = (const float*)d_in[1];
  const float* rb    = (const float*)d_in[2];
  const float* rg    = (const float*)d_in[3];
  const float* rbb   = (const float*)d_in[4];
  const float* rm    = (const float*)d_in[5];
  const float* rv    = (const float*)d_in[6];
  const float* fc1_w = (const float*)d_in[7];
  const float* fc1_b = (const float*)d_in[8];
  const float* bn1_g = (const float*)d_in[9];
  const float* bn1_b = (const float*)d_in[10];
  const float* bn1_m = (const float*)d_in[11];
  const float* bn1_v = (const float*)d_in[12];
  const float* fc2_w = (const float*)d_in[13];
  const float* fc2_b = (const float*)d_in[14];
  const float* bn2_g = (const float*)d_in[15];
  const float* bn2_b = (const float*)d_in[16];
  const float* bn2_m = (const float*)d_in[17];
  const float* bn2_v = (const float*)d_in[18];
  const float* taus  = (const float*)d_in[19];
  float* out = (float*)d_out;

  char* ws = (char*)d_ws;
  size_t off = 0;
  auto alloc = [&](size_t bytes) -> char* {
    char* p = ws + off;
    off = (off + bytes + 255) & ~(size_t)255;
    return p;
  };
  const int NW = E_ * HID_ * C_;                                   // 2,097,152
  unsigned short* s2  = (unsigned short*)alloc((size_t)NPAIR_ * M_ * HID_ * 2); // 25.7MB
  unsigned short* w2h = (unsigned short*)alloc((size_t)NW * 2);                 // 4.2MB
  unsigned short* w1h = (unsigned short*)alloc((size_t)NW * 2);                 // 4.2MB
  unsigned short* w1l = (unsigned short*)alloc((size_t)NW * 2);                 // 4.2MB
  unsigned short* s1  = (unsigned short*)alloc((size_t)NPAIR_ * M_ * C_ * 2);   // 6.4MB
  float* xbar  = (float*)alloc(B_ * C_ * 4);
  int*   sel_e = (int*)alloc(NPAIR_ * 4);
  float* sel_w = (float*)alloc(NPAIR_ * 4);
  // y (2 slots, out-layout f32, 12.8MB) overlays w1h+w1l+s1 (14.8MB): those are
  // dead after g1, rewritten by wconv/lif1 every call.
  float* y = (float*)w1h;
  (void)ws_size; (void)in_sizes; (void)n_in; (void)out_size;

  wconv_kernel<<<NW / 4 / 256, 256, 0, stream>>>(fc1_w, fc2_w, w1h, w1l, w2h);
  xbar_kernel<<<B_ * C_, 64, 0, stream>>>(x, xbar);
  router_kernel<<<1, 64, 0, stream>>>(xbar, rw, rb, rg, rbb, rm, rv, sel_e, sel_w);
  lif1_kernel<<<dim3(HW_, NPAIR_), 256, 0, stream>>>(x, sel_e, taus, s1);
  g1_kernel<<<dim3(HID_ / 64, (M_ + 63) / 64, NPAIR_), 256, 0, stream>>>(
      s1, w1h, w1l, fc1_b, bn1_g, bn1_b, bn1_m, bn1_v, sel_e, taus, s2);
  g2_kernel<<<dim3(C_ / 64, (M_ + 63) / 64, NPAIR_), 256, 0, stream>>>(
      s2, w2h, fc2_b, bn2_g, bn2_b, bn2_m, bn2_v, sel_e, sel_w, y);
  combine_kernel<<<NOUT_ / 4 / 256, 256, 0, stream>>>(x, y, out);
}

// Round 11
// 193.938 us; speedup vs baseline: 1.0198x; 1.0198x over previous
//
#include <hip/hip_runtime.h>
#include <hip/hip_bf16.h>
#include <math.h>

#define T_ 4
#define B_ 8
#define C_ 256
#define HID_ 1024
#define E_ 8
#define HW_ 196
#define M_ 784            // T*HW rows per (b,expert) pair, r = hw*4 + t
#define NPAIR_ 16
#define EPS_ 1e-5f
#define NOUT_ (T_*B_*C_*HW_)   // 1,605,632 floats

typedef __attribute__((ext_vector_type(8))) short bf16x8;
typedef __attribute__((ext_vector_type(4))) unsigned short u16x4;
typedef __attribute__((ext_vector_type(4))) float f32x4;

__device__ inline unsigned short f2bf(float f){
  union { float f; unsigned u; } v; v.f = f;
  unsigned u = v.u;
  unsigned r = u + 0x7FFFu + ((u >> 16) & 1u);   // RNE
  return (unsigned short)(r >> 16);
}
__device__ inline float bf2f(unsigned short h){
  union { unsigned u; float f; } v; v.u = ((unsigned)h) << 16;
  return v.f;
}

// direct global->LDS, 16B/lane; LDS dest = wave-uniform base + lane*16
__device__ inline void gl16(const void* g, void* l){
  auto gp = reinterpret_cast<const unsigned int __attribute__((address_space(1)))*>(
      reinterpret_cast<uintptr_t>(g));
  auto lp = reinterpret_cast<unsigned int __attribute__((address_space(3)))*>(
      reinterpret_cast<uintptr_t>(l));
  __builtin_amdgcn_global_load_lds(gp, lp, 16, 0, 0);
}

// ---- prep: blocks [0,2048) = weight conversion; [2048,2560) = xbar ----
__global__ __launch_bounds__(256) void prep_kernel(
    const float* __restrict__ w1, const float* __restrict__ w2,
    const float* __restrict__ x,
    unsigned short* __restrict__ w1h, unsigned short* __restrict__ w1l,
    unsigned short* __restrict__ w2h, float* __restrict__ xbar){
  const int blk = blockIdx.x;
  if (blk < 2048){
    int i = blk * 256 + threadIdx.x;           // over NW/4
    float4 v = ((const float4*)w1)[i];
    u16x4 h, l;
    h[0]=f2bf(v.x); l[0]=f2bf(v.x - bf2f(h[0]));
    h[1]=f2bf(v.y); l[1]=f2bf(v.y - bf2f(h[1]));
    h[2]=f2bf(v.z); l[2]=f2bf(v.z - bf2f(h[2]));
    h[3]=f2bf(v.w); l[3]=f2bf(v.w - bf2f(h[3]));
    ((u16x4*)w1h)[i] = h; ((u16x4*)w1l)[i] = l;
    float4 u = ((const float4*)w2)[i];
    u16x4 h2;
    h2[0]=f2bf(u.x); h2[1]=f2bf(u.y); h2[2]=f2bf(u.z); h2[3]=f2bf(u.w);
    ((u16x4*)w2h)[i] = h2;
  } else {
    const int q = blk - 2048;                  // 0..511
    const int g = threadIdx.x >> 6;            // wave id = group
    const int lane = threadIdx.x & 63;
    const int bc = q * 4 + g;                  // 0..2047
    float s = 0.f;
    for (int t = 0; t < T_; t++){
      const float* p = x + ((size_t)(t * B_ * C_) + bc) * HW_;
      for (int i = lane; i < HW_; i += 64) s += p[i];
    }
    for (int off = 32; off > 0; off >>= 1) s += __shfl_down(s, off, 64);
    if (lane == 0) xbar[bc] = s * (1.0f / (T_ * HW_));
  }
}

// ---- router: logits -> softmax -> top2 ----
__global__ __launch_bounds__(64) void router_kernel(const float* __restrict__ xbar,
    const float* __restrict__ rw, const float* __restrict__ rb,
    const float* __restrict__ rg, const float* __restrict__ rbb,
    const float* __restrict__ rm, const float* __restrict__ rv,
    int* __restrict__ sel_e, float* __restrict__ sel_w){
  __shared__ float lg[64];
  const int tid = threadIdx.x;
  const int b = tid >> 3, e = tid & 7;
  float dot = 0.f;
  for (int c = 0; c < C_; c++) dot += xbar[b * C_ + c] * rw[e * C_ + c];
  dot += rb[e];
  float sc = rg[e] / sqrtf(rv[e] + EPS_);
  lg[tid] = (dot - rm[e]) * sc + rbb[e];
  __syncthreads();
  if (e == 0){
    float l[E_], mx = -1e30f;
    for (int i = 0; i < E_; i++){ l[i] = lg[b * 8 + i]; mx = fmaxf(mx, l[i]); }
    float p[E_];
    for (int i = 0; i < E_; i++) p[i] = expf(l[i] - mx);
    int i1 = 0;
    for (int i = 1; i < E_; i++) if (p[i] > p[i1]) i1 = i;
    int i2 = (i1 == 0) ? 1 : 0;
    for (int i = 0; i < E_; i++) if (i != i1 && p[i] > p[i2]) i2 = i;
    float denom = p[i1] + p[i2];
    sel_e[b * 2]     = i1; sel_w[b * 2]     = p[i1] / denom;
    sel_e[b * 2 + 1] = i2; sel_w[b * 2 + 1] = p[i2] / denom;
  }
}

// ---- LIF1 (coalesced reads): thread f = c*HW+hw; x reads contiguous in f ----
__global__ __launch_bounds__(256) void lif1_kernel(const float* __restrict__ x,
    const int* __restrict__ sel_e, const float* __restrict__ taus,
    unsigned short* __restrict__ s1){
  const int pair = blockIdx.y;
  const int b = pair >> 1;
  const int f = blockIdx.x * 256 + threadIdx.x;   // 0..50175 = C*HW
  const int c = f / HW_, hw = f - c * HW_;
  const float tau = taus[sel_e[pair]];
  unsigned short* o = s1 + (size_t)pair * (M_ * C_) + (size_t)(hw * 4) * C_ + c;
  float v = 0.f;
  #pragma unroll
  for (int t = 0; t < T_; t++){
    float xv = x[(size_t)(t * B_ + b) * (C_ * HW_) + f];   // coalesced
    float h = v + (xv - v) / tau;
    float s = (h >= 1.0f) ? 1.0f : 0.0f;
    v = h * (1.0f - s);
    o[t * C_] = (s > 0.5f) ? (unsigned short)0x3F80 : (unsigned short)0;
  }
}

// Bank swizzle: LDS tile [64 rows][32 u16], 16B slot s of row r stored at
// phys slot s ^ (r&3) ^ ((r>>2)&1). Staging pre-swizzles the GLOBAL source
// column (inverse-swz source + swz read, LDS dest stays linear).

// ---- GEMM1: grid (nt16, mt13, pair16); 48KB LDS 4-buf ring; counted vmcnt;
// hi/lo MFMA; BN1+LIF2 in-register epilogue -> s2 ----
__global__ __launch_bounds__(256) void g1_kernel(
    const unsigned short* __restrict__ s1,
    const unsigned short* __restrict__ w1h, const unsigned short* __restrict__ w1l,
    const float* __restrict__ fc1_b,
    const float* __restrict__ bn1_g, const float* __restrict__ bn1_b,
    const float* __restrict__ bn1_m, const float* __restrict__ bn1_v,
    const int* __restrict__ sel_e, const float* __restrict__ taus,
    unsigned short* __restrict__ s2)
{
  __shared__ __align__(16) unsigned short lA[4][2048];
  __shared__ __align__(16) unsigned short lBh[4][2048];
  __shared__ __align__(16) unsigned short lBl[4][2048];
  const int nt = blockIdx.x, mt = blockIdx.y, pair = blockIdx.z;
  const int e = sel_e[pair];
  const int m0 = mt * 64, n0 = nt * 64;
  const int tid = threadIdx.x, lane = tid & 63, wv = tid >> 6;
  const int l15 = lane & 15;
  const int koffs = ((((lane >> 4) ^ (l15 & 3) ^ ((l15 >> 2) & 1)) & 3) << 3);
  const int srow = wv * 16 + (lane >> 2);
  const int scol = ((((lane & 3) ^ ((lane >> 2) & 3) ^ ((lane >> 4) & 1)) & 3) << 3);
  int arow = m0 + srow; if (arow > M_ - 1) arow = M_ - 1;   // clamp; dup discarded
  const unsigned short* aG  = s1  + ((size_t)pair * M_ + arow) * C_ + scol;
  const unsigned short* bhG = w1h + ((size_t)e * HID_ + n0 + srow) * C_ + scol;
  const unsigned short* blG = w1l + ((size_t)e * HID_ + n0 + srow) * C_ + scol;
  const int lb = wv * 512;
  #pragma unroll
  for (int p = 0; p < 3; p++){
    gl16(aG  + p * 32, &lA[p][lb]);
    gl16(bhG + p * 32, &lBh[p][lb]);
    gl16(blG + p * 32, &lBl[p][lb]);
  }
  f32x4 acc[4] = {};
  #pragma unroll
  for (int kk = 0; kk < 8; kk++){
    if (kk < 6)       asm volatile("s_waitcnt vmcnt(6)" ::: "memory");
    else if (kk == 6) asm volatile("s_waitcnt vmcnt(3)" ::: "memory");
    else              asm volatile("s_waitcnt vmcnt(0)" ::: "memory");
    __builtin_amdgcn_s_barrier();
    __builtin_amdgcn_sched_barrier(0);
    const int cur = kk & 3;
    bf16x8 a = *(const bf16x8*)(&lA[cur][(wv * 16 + l15) * 32 + koffs]);
    #pragma unroll
    for (int cb = 0; cb < 4; cb++){
      bf16x8 bh = *(const bf16x8*)(&lBh[cur][(cb * 16 + l15) * 32 + koffs]);
      bf16x8 bl = *(const bf16x8*)(&lBl[cur][(cb * 16 + l15) * 32 + koffs]);
      acc[cb] = __builtin_amdgcn_mfma_f32_16x16x32_bf16(a, bh, acc[cb], 0, 0, 0);
      acc[cb] = __builtin_amdgcn_mfma_f32_16x16x32_bf16(a, bl, acc[cb], 0, 0, 0);
    }
    if (kk < 5){
      const int nb = (kk + 3) & 3;
      gl16(aG  + (kk + 3) * 32, &lA[nb][lb]);
      gl16(bhG + (kk + 3) * 32, &lBh[nb][lb]);
      gl16(blG + (kk + 3) * 32, &lBl[nb][lb]);
    }
  }
  const float tau = taus[e];
  const int rbase = m0 + wv * 16 + ((lane >> 4) << 2);
  if (rbase < M_){
    #pragma unroll
    for (int cb = 0; cb < 4; cb++){
      int col = n0 + cb * 16 + l15;
      int pi = e * HID_ + col;
      float sc = bn1_g[pi] / sqrtf(bn1_v[pi] + EPS_);
      float mm = bn1_m[pi], bb = bn1_b[pi], cbias = fc1_b[pi];
      float v = 0.f;
      #pragma unroll
      for (int t = 0; t < 4; t++){
        float z = acc[cb][t] + cbias;
        float hin = (z - mm) * sc + bb;
        float h = v + (hin - v) / tau;
        float s = (h >= 1.0f) ? 1.0f : 0.0f;
        v = h * (1.0f - s);
        s2[((size_t)pair * M_ + rbase + t) * HID_ + col] =
            (s > 0.5f) ? (unsigned short)0x3F80 : (unsigned short)0;
      }
    }
  }
}

// ---- GEMM2 fused: grid (nt4, mt13, b8); both slots per block; hi-only;
// BN2 + combine-weight folded; writes out = x + y0 + y1 directly ----
__global__ __launch_bounds__(256) void g2_kernel(
    const unsigned short* __restrict__ s2,
    const unsigned short* __restrict__ w2h,
    const float* __restrict__ fc2_b,
    const float* __restrict__ bn2_g, const float* __restrict__ bn2_b,
    const float* __restrict__ bn2_m, const float* __restrict__ bn2_v,
    const int* __restrict__ sel_e, const float* __restrict__ sel_w,
    const float* __restrict__ x, float* __restrict__ out)
{
  __shared__ __align__(16) unsigned short lA[4][2048];
  __shared__ __align__(16) unsigned short lBh[4][2048];
  const int nt = blockIdx.x, mt = blockIdx.y, b = blockIdx.z;
  const int m0 = mt * 64, n0 = nt * 64;
  const int tid = threadIdx.x, lane = tid & 63, wv = tid >> 6;
  const int l15 = lane & 15;
  const int koffs = ((((lane >> 4) ^ (l15 & 3) ^ ((l15 >> 2) & 1)) & 3) << 3);
  const int srow = wv * 16 + (lane >> 2);
  const int scol = ((((lane & 3) ^ ((lane >> 2) & 3) ^ ((lane >> 4) & 1)) & 3) << 3);
  int arow = m0 + srow; if (arow > M_ - 1) arow = M_ - 1;
  const int lb = wv * 512;
  f32x4 res[4] = {};
  for (int slot = 0; slot < 2; slot++){
    const int pair = b * 2 + slot;
    const int e = sel_e[pair];
    const float wgt = sel_w[pair];
    const unsigned short* aG  = s2  + ((size_t)pair * M_ + arow) * HID_ + scol;
    const unsigned short* bhG = w2h + ((size_t)e * C_ + n0 + srow) * HID_ + scol;
    #pragma unroll
    for (int p = 0; p < 3; p++){
      gl16(aG  + p * 32, &lA[p][lb]);
      gl16(bhG + p * 32, &lBh[p][lb]);
    }
    f32x4 acc[4] = {};
    #pragma unroll
    for (int kk = 0; kk < 32; kk++){
      if (kk < 30)       asm volatile("s_waitcnt vmcnt(4)" ::: "memory");
      else if (kk == 30) asm volatile("s_waitcnt vmcnt(2)" ::: "memory");
      else               asm volatile("s_waitcnt vmcnt(0)" ::: "memory");
      __builtin_amdgcn_s_barrier();
      __builtin_amdgcn_sched_barrier(0);
      const int cur = kk & 3;
      bf16x8 a = *(const bf16x8*)(&lA[cur][(wv * 16 + l15) * 32 + koffs]);
      #pragma unroll
      for (int cb = 0; cb < 4; cb++){
        bf16x8 bh = *(const bf16x8*)(&lBh[cur][(cb * 16 + l15) * 32 + koffs]);
        acc[cb] = __builtin_amdgcn_mfma_f32_16x16x32_bf16(a, bh, acc[cb], 0, 0, 0);
      }
      if (kk < 29){
        const int nb = (kk + 3) & 3;
        gl16(aG  + (kk + 3) * 32, &lA[nb][lb]);
        gl16(bhG + (kk + 3) * 32, &lBh[nb][lb]);
      }
    }
    // fold this slot: BN2 + combine weight
    #pragma unroll
    for (int cb = 0; cb < 4; cb++){
      int col = n0 + cb * 16 + l15;
      int pi = e * C_ + col;
      float sc = bn2_g[pi] / sqrtf(bn2_v[pi] + EPS_);
      float mm = bn2_m[pi], bb = bn2_b[pi], cbias = fc2_b[pi];
      #pragma unroll
      for (int t = 0; t < 4; t++){
        float z = acc[cb][t] + cbias;
        res[cb][t] += wgt * ((z - mm) * sc + bb);
      }
    }
    __syncthreads();   // all reads of ring bufs done before next slot's prologue
  }
  const int rbase = m0 + wv * 16 + ((lane >> 4) << 2);
  if (rbase < M_){
    const int hw = rbase >> 2;
    #pragma unroll
    for (int cb = 0; cb < 4; cb++){
      int col = n0 + cb * 16 + l15;
      #pragma unroll
      for (int t = 0; t < 4; t++){
        size_t oi = ((size_t)(t * B_ + b) * C_ + col) * HW_ + hw;
        out[oi] = x[oi] + res[cb][t];
      }
    }
  }
}

extern "C" void kernel_launch(void* const* d_in, const int* in_sizes, int n_in,
                              void* d_out, int out_size, void* d_ws, size_t ws_size,
                              hipStream_t stream){
  const float* x     = (const float*)d_in[0];
  const float* rw    = (const float*)d_in[1];
  const float* rb    = (const float*)d_in[2];
  const float* rg    = (const float*)d_in[3];
  const float* rbb   = (const float*)d_in[4];
  const float* rm    = (const float*)d_in[5];
  const float* rv    = (const float*)d_in[6];
  const float* fc1_w = (const float*)d_in[7];
  const float* fc1_b = (const float*)d_in[8];
  const float* bn1_g = (const float*)d_in[9];
  const float* bn1_b = (const float*)d_in[10];
  const float* bn1_m = (const float*)d_in[11];
  const float* bn1_v = (const float*)d_in[12];
  const float* fc2_w = (const float*)d_in[13];
  const float* fc2_b = (const float*)d_in[14];
  const float* bn2_g = (const float*)d_in[15];
  const float* bn2_b = (const float*)d_in[16];
  const float* bn2_m = (const float*)d_in[17];
  const float* bn2_v = (const float*)d_in[18];
  const float* taus  = (const float*)d_in[19];
  float* out = (float*)d_out;

  char* ws = (char*)d_ws;
  size_t off = 0;
  auto alloc = [&](size_t bytes) -> char* {
    char* p = ws + off;
    off = (off + bytes + 255) & ~(size_t)255;
    return p;
  };
  const int NW = E_ * HID_ * C_;                                   // 2,097,152
  unsigned short* s2  = (unsigned short*)alloc((size_t)NPAIR_ * M_ * HID_ * 2); // 25.7MB
  unsigned short* w2h = (unsigned short*)alloc((size_t)NW * 2);                 // 4.2MB
  unsigned short* w1h = (unsigned short*)alloc((size_t)NW * 2);                 // 4.2MB
  unsigned short* w1l = (unsigned short*)alloc((size_t)NW * 2);                 // 4.2MB
  unsigned short* s1  = (unsigned short*)alloc((size_t)NPAIR_ * M_ * C_ * 2);   // 6.4MB
  float* xbar  = (float*)alloc(B_ * C_ * 4);
  int*   sel_e = (int*)alloc(NPAIR_ * 4);
  float* sel_w = (float*)alloc(NPAIR_ * 4);
  (void)ws_size; (void)in_sizes; (void)n_in; (void)out_size;

  prep_kernel<<<2560, 256, 0, stream>>>(fc1_w, fc2_w, x, w1h, w1l, w2h, xbar);
  router_kernel<<<1, 64, 0, stream>>>(xbar, rw, rb, rg, rbb, rm, rv, sel_e, sel_w);
  lif1_kernel<<<dim3((C_ * HW_) / 256, NPAIR_), 256, 0, stream>>>(x, sel_e, taus, s1);
  g1_kernel<<<dim3(HID_ / 64, (M_ + 63) / 64, NPAIR_), 256, 0, stream>>>(
      s1, w1h, w1l, fc1_b, bn1_g, bn1_b, bn1_m, bn1_v, sel_e, taus, s2);
  g2_kernel<<<dim3(C_ / 64, (M_ + 63) / 64, B_), 256, 0, stream>>>(
      s2, w2h, fc2_b, bn2_g, bn2_b, bn2_m, bn2_v, sel_e, sel_w, x, out);
}